// Round 6
// baseline (113.499 us; speedup 1.0000x reference)
//
#include <hip/hip_runtime.h>
#include <cstdint>

typedef float   f32x4  __attribute__((ext_vector_type(4)));
typedef __bf16  bf16x4 __attribute__((ext_vector_type(4)));
typedef __bf16  bf16x8 __attribute__((ext_vector_type(8)));

#if __has_builtin(__builtin_amdgcn_exp2f)
#define EXP2F(x) __builtin_amdgcn_exp2f(x)
#else
#define EXP2F(x) exp2f(x)
#endif

#define BT_TOTAL 512
#define NNODES 170
#define CDIM 128
#define HEADS 8
#define HDIM 16
#define SLAB (NNODES*HDIM)           // 2720
#define NPAD 176                     // V^T row stride
#define VSLAB (HDIM*NPAD)            // 2816
#define QKV_ELEMS ((size_t)BT_TOTAL*HEADS*SLAB)
#define WPAD 136                     // oproj LDS W row stride
#define S2L2E 0.12753851f            // log2(e)/sqrt(128), folded into Wq/bq
#define MROWS (BT_TOTAL*NNODES)      // 87040 = 64 * 1360
#define BLKS_PER_IID 1360

__device__ __forceinline__ void gload_lds16(const float* g, float* l) {
    __builtin_amdgcn_global_load_lds((const __attribute__((address_space(1))) uint32_t*)g,
                                     (__attribute__((address_space(3))) uint32_t*)l, 16, 0, 0);
}

// ---------------------------------------------------------------- W -> bf16, k-swizzled
// wbf[mat][c][kk*32 + l4*8 + j] = W[mat][c][kk*32 + l4*4 + (j&3) + 16*(j>>2)]
__global__ __launch_bounds__(256) void wconv_kernel(const float* __restrict__ wq,
                                                    const float* __restrict__ wk,
                                                    const float* __restrict__ wv,
                                                    const float* __restrict__ wo,
                                                    __bf16* __restrict__ wbf) {
    int idx = blockIdx.x * 256 + threadIdx.x;
    if (idx >= 4 * 16384) return;
    int mat = idx >> 14, rem = idx & 16383;
    int c = rem >> 7, o = rem & 127;
    int kk = o >> 5, l4 = (o & 31) >> 3, j = o & 7;
    int col = kk * 32 + l4 * 4 + (j & 3) + 16 * (j >> 2);
    const float* W = (mat == 0) ? wq : (mat == 1) ? wk : (mat == 2) ? wv : wo;
    float scale = (mat == 0) ? S2L2E : 1.0f;
    wbf[idx] = (__bf16)(W[c * 128 + col] * scale);
}

// ---------------------------------------------------------------- QKV projection, LDS-staged
// grid = 3*1360 blocks x 256 thr (4 waves). Block = 64 global rows (2 tiles of 32),
// X-tile staged via global_load_lds with additive chunk swizzle; W in registers.
// wave: (w&1) = row-subtile, (w>>1) = channel half (64 ch).
__global__ __launch_bounds__(256, 4) void qkv_kernel(const float* __restrict__ qin,
    const float* __restrict__ kin, const float* __restrict__ vin,
    const __bf16* __restrict__ wbf,
    const float* __restrict__ bq, const float* __restrict__ bk, const float* __restrict__ bv,
    __bf16* __restrict__ qws, __bf16* __restrict__ kws, __bf16* __restrict__ vt) {
    __shared__ __align__(16) float Xl[2][32 * 128];    // 2 x 16 KB

    int bid = blockIdx.x;
    int iid = bid / BLKS_PER_IID, blk = bid % BLKS_PER_IID;
    const float* X    = (iid == 0) ? qin : (iid == 1) ? kin : vin;
    const float* bias = (iid == 0) ? bq  : (iid == 1) ? bk  : bv;
    float wscale = (iid == 0) ? S2L2E : 1.0f;
    int t = threadIdx.x, w = t >> 6, lane = t & 63, li = lane & 15, l4 = lane >> 4;
    int gbase = blk * 64;
    int ch = (w >> 1) * 64;
    int wt = w & 1;

    // W fragments in registers (16 x bf16x8 = 64 VGPR), L2/L3-hot
    const __bf16* wb = wbf + iid * 16384;
    bf16x8 wf[4][4];
    #pragma unroll
    for (int nt = 0; nt < 4; ++nt)
        #pragma unroll
        for (int kk = 0; kk < 4; ++kk)
            wf[nt][kk] = *(const bf16x8*)&wb[(ch + nt * 16 + li) * 128 + kk * 32 + l4 * 8];

    // stage 32 rows (16KB) into Xl[buf]: wave w stages rows w*8..w*8+7, 4 instr x 1KB.
    // LDS linear; source pre-swizzled: physical chunk pc holds logical (pc - 4*(r&7))&31.
    auto stage = [&](int buf, int tt) {
        float* dst0 = &Xl[buf][w * 8 * 128];
        int g0 = gbase + tt * 32 + w * 8;
        int rloc = (lane >> 5);                      // 0/1 within instr pair
        int pc = lane & 31;
        #pragma unroll
        for (int i = 0; i < 4; ++i) {
            int r = 2 * i + rloc;                    // 0..7 within wave's rows
            int lc = (pc - 4 * (r & 7)) & 31;
            const float* src = X + (size_t)(g0 + r) * 128 + lc * 4;
            gload_lds16(src, dst0 + i * 256);
        }
    };

    auto compute = [&](int buf, int tt) {
        int r = wt * 16 + li;                        // row within 32-row tile
        f32x4 acc[4] = {};
        #pragma unroll
        for (int kk = 0; kk < 4; ++kk) {
            int p1 = (8 * kk + l4 + 4 * (li & 7)) & 31;
            int p2 = (8 * kk + l4 + 4 + 4 * (li & 7)) & 31;
            f32x4 a0 = *(const f32x4*)&Xl[buf][r * 128 + p1 * 4];
            f32x4 a1 = *(const f32x4*)&Xl[buf][r * 128 + p2 * 4];
            bf16x8 a = { (__bf16)a0[0], (__bf16)a0[1], (__bf16)a0[2], (__bf16)a0[3],
                         (__bf16)a1[0], (__bf16)a1[1], (__bf16)a1[2], (__bf16)a1[3] };
            if (iid < 2) {
                #pragma unroll
                for (int nt = 0; nt < 4; ++nt)       // swapped: col=li=row(node), C-rows=channels
                    acc[nt] = __builtin_amdgcn_mfma_f32_16x16x32_bf16(wf[nt][kk], a, acc[nt], 0, 0, 0);
            } else {
                #pragma unroll
                for (int nt = 0; nt < 4; ++nt)       // unswapped: col=li=channel, C-rows=nodes
                    acc[nt] = __builtin_amdgcn_mfma_f32_16x16x32_bf16(a, wf[nt][kk], acc[nt], 0, 0, 0);
            }
        }
        if (iid < 2) {
            int g = gbase + tt * 32 + wt * 16 + li;
            int bt = g / 170, n = g - bt * 170;
            __bf16* base = ((iid == 0) ? qws : kws);
            #pragma unroll
            for (int nt = 0; nt < 4; ++nt) {
                int h = (w >> 1) * 4 + nt;
                f32x4 b4 = *(const f32x4*)&bias[ch + nt * 16 + l4 * 4];
                f32x4 ov = acc[nt] + b4 * wscale;
                bf16x4 o4 = { (__bf16)ov[0], (__bf16)ov[1], (__bf16)ov[2], (__bf16)ov[3] };
                *(bf16x4*)&base[((size_t)(bt * HEADS + h)) * SLAB + n * HDIM + l4 * 4] = o4;
            }
        } else {
            int n0g = gbase + tt * 32 + wt * 16 + 4 * l4;
            int bt0 = n0g / 170, n0 = n0g - bt0 * 170;
            #pragma unroll
            for (int nt = 0; nt < 4; ++nt) {
                int h = (w >> 1) * 4 + nt;           // d = li
                float bval = bias[ch + nt * 16 + li];
                if (n0 <= 166) {
                    bf16x4 o4 = { (__bf16)(acc[nt][0] + bval), (__bf16)(acc[nt][1] + bval),
                                  (__bf16)(acc[nt][2] + bval), (__bf16)(acc[nt][3] + bval) };
                    *(bf16x4*)&vt[((size_t)(bt0 * HEADS + h)) * VSLAB + li * NPAD + n0] = o4;
                } else {
                    #pragma unroll
                    for (int rr = 0; rr < 4; ++rr) {
                        int g = n0g + rr;
                        int bt = g / 170, n = g - bt * 170;
                        vt[((size_t)(bt * HEADS + h)) * VSLAB + li * NPAD + n] = (__bf16)(acc[nt][rr] + bval);
                    }
                }
            }
        }
    };

    stage(0, 0);
    __syncthreads();          // drains stage-0
    stage(1, 1);              // prefetch overlaps compute-0
    compute(0, 0);
    __syncthreads();          // drains stage-1
    compute(1, 1);
}

// ---------------------------------------------------------------- attention core
// 4 independent wave-units per 256-thread block; unit = (bt, h, q-half).
// O stored in k-swizzled column order for oproj's contiguous bf16x8 A-loads.
__global__ __launch_bounds__(256) void attn_kernel(const __bf16* __restrict__ qws,
                                                   const __bf16* __restrict__ kws,
                                                   const __bf16* __restrict__ vt,
                                                   __bf16* __restrict__ ows) {
    int unit = blockIdx.x * 4 + (threadIdx.x >> 6);
    int half = unit & 1, bh = unit >> 1;
    int bt = bh >> 3, h = bh & 7;
    int lane = threadIdx.x & 63, li = lane & 15, l4 = lane >> 4;
    const __bf16* qb  = qws + ((size_t)(bt * HEADS + h)) * SLAB;
    const __bf16* kb  = kws + ((size_t)(bt * HEADS + h)) * SLAB;
    const __bf16* vtb = vt  + ((size_t)(bt * HEADS + h)) * VSLAB;
    __bf16* ob = ows + (size_t)bt * NNODES * CDIM + (h >> 1) * 32 + (h & 1) * 4;
    const __bf16 bz = (__bf16)0.0f;
    const bf16x4 z4 = {bz, bz, bz, bz};
    const f32x4 zf = {0.f, 0.f, 0.f, 0.f};

    bf16x4 kf[11];
    #pragma unroll
    for (int tt = 0; tt < 11; ++tt)
        kf[tt] = *(const bf16x4*)&kb[(tt * 16 + li) * HDIM + l4 * 4];

    bf16x8 vf[6];
    #pragma unroll
    for (int s = 0; s < 5; ++s) {
        bf16x4 a = *(const bf16x4*)&vtb[li * NPAD + 32 * s + 4 * l4];
        bf16x4 b = *(const bf16x4*)&vtb[li * NPAD + 32 * s + 4 * l4 + 16];
        vf[s] = __builtin_shufflevector(a, b, 0, 1, 2, 3, 4, 5, 6, 7);
    }
    {
        bf16x4 a = *(const bf16x4*)&vtb[li * NPAD + 160 + 4 * l4];
        bf16x8 v5 = { (160 + 4 * l4 + 0 < NNODES) ? a[0] : bz,
                      (160 + 4 * l4 + 1 < NNODES) ? a[1] : bz,
                      (160 + 4 * l4 + 2 < NNODES) ? a[2] : bz,
                      (160 + 4 * l4 + 3 < NNODES) ? a[3] : bz,
                      bz, bz, bz, bz };
        vf[5] = v5;
    }

    int q0 = half ? 6 : 0;
    int qn = half ? 5 : 6;
    for (int qi = 0; qi < qn; ++qi) {
        int qc = q0 + qi;
        bf16x4 qv = *(const bf16x4*)&qb[(qc * 16 + li) * HDIM + l4 * 4];
        bf16x8 qf = __builtin_shufflevector(qv, z4, 0, 1, 2, 3, 4, 5, 6, 7);
        bf16x4 ph[11];
        f32x4 s4 = zf;
        #pragma unroll
        for (int tt = 0; tt < 11; ++tt) {
            bf16x8 a = __builtin_shufflevector(kf[tt], z4, 0, 1, 2, 3, 4, 5, 6, 7);
            f32x4 e = __builtin_amdgcn_mfma_f32_16x16x32_bf16(a, qf, zf, 0, 0, 0);
            if (tt == 10) {   // select BEFORE exp2: NaN-safe for unwritten K rows
                #pragma unroll
                for (int r = 0; r < 4; ++r)
                    e[r] = (160 + l4 * 4 + r < NNODES) ? e[r] : -1.0e30f;
            }
            f32x4 p;
            p[0] = EXP2F(e[0]); p[1] = EXP2F(e[1]);
            p[2] = EXP2F(e[2]); p[3] = EXP2F(e[3]);
            s4 += p;
            ph[tt] = __builtin_convertvector(p, bf16x4);
        }
        float sum = (s4[0] + s4[1]) + (s4[2] + s4[3]);
        sum += __shfl_xor(sum, 16);
        sum += __shfl_xor(sum, 32);
        float inv = 1.0f / sum;
        f32x4 o0 = zf, o1 = zf;
        o0 = __builtin_amdgcn_mfma_f32_16x16x32_bf16(vf[0],
                __builtin_shufflevector(ph[0], ph[1], 0,1,2,3,4,5,6,7), o0, 0,0,0);
        o1 = __builtin_amdgcn_mfma_f32_16x16x32_bf16(vf[1],
                __builtin_shufflevector(ph[2], ph[3], 0,1,2,3,4,5,6,7), o1, 0,0,0);
        o0 = __builtin_amdgcn_mfma_f32_16x16x32_bf16(vf[2],
                __builtin_shufflevector(ph[4], ph[5], 0,1,2,3,4,5,6,7), o0, 0,0,0);
        o1 = __builtin_amdgcn_mfma_f32_16x16x32_bf16(vf[3],
                __builtin_shufflevector(ph[6], ph[7], 0,1,2,3,4,5,6,7), o1, 0,0,0);
        o0 = __builtin_amdgcn_mfma_f32_16x16x32_bf16(vf[4],
                __builtin_shufflevector(ph[8], ph[9], 0,1,2,3,4,5,6,7), o0, 0,0,0);
        o1 = __builtin_amdgcn_mfma_f32_16x16x32_bf16(vf[5],
                __builtin_shufflevector(ph[10], z4,    0,1,2,3,4,5,6,7), o1, 0,0,0);
        f32x4 o = (o0 + o1) * inv;
        int q = qc * 16 + li;
        if (q < NNODES) {
            bf16x4 ov = { (__bf16)o[0], (__bf16)o[1], (__bf16)o[2], (__bf16)o[3] };
            *(bf16x4*)&ob[(size_t)q * CDIM + l4 * 8] = ov;
        }
    }
}

// ---------------------------------------------------------------- output projection
__global__ __launch_bounds__(512) void oproj_kernel(const __bf16* __restrict__ ows,
                                                    const __bf16* __restrict__ wbf,
                                                    const float* __restrict__ bo,
                                                    float* __restrict__ out) {
    __shared__ __bf16 Wl[128 * WPAD];
    int t = threadIdx.x;
    int bt = blockIdx.x;
    const __bf16* wo = wbf + 3 * 16384;
    #pragma unroll
    for (int i = 0; i < 4; ++i) {
        int idx = i * 512 + t;
        int c = idx >> 4, x = (idx & 15) * 8;
        *(bf16x8*)&Wl[c * WPAD + x] = *(const bf16x8*)&wo[idx * 8];
    }
    __syncthreads();

    int w = t >> 6, lane = t & 63, li = lane & 15, l4 = lane >> 4;
    const bf16x8 z8 = {};

    auto loadO = [&](bf16x8* A, int tile) {
        int mrow = tile * 16 + li;
        bool v = mrow < NNODES;
        const __bf16* ar = ows + ((size_t)(bt * NNODES + mrow)) * CDIM;
        #pragma unroll
        for (int kk = 0; kk < 4; ++kk)
            A[kk] = v ? *(const bf16x8*)(ar + kk * 32 + l4 * 8) : z8;
    };
    auto computeO = [&](const bf16x8* A, int tile) {
        f32x4 acc[8] = {};
        #pragma unroll
        for (int kk = 0; kk < 4; ++kk) {
            #pragma unroll
            for (int nt = 0; nt < 8; ++nt) {
                bf16x8 b = *(const bf16x8*)&Wl[(nt * 16 + li) * WPAD + kk * 32 + l4 * 8];
                acc[nt] = __builtin_amdgcn_mfma_f32_16x16x32_bf16(b, A[kk], acc[nt], 0, 0, 0);
            }
        }
        int n = tile * 16 + li;
        if (n < NNODES) {
            float* orow = out + ((size_t)bt * NNODES + n) * CDIM;
            #pragma unroll
            for (int nt = 0; nt < 8; ++nt) {
                f32x4 b4 = *(const f32x4*)&bo[nt * 16 + l4 * 4];
                *(f32x4*)&orow[nt * 16 + l4 * 4] = acc[nt] + b4;
            }
        }
    };

    bf16x8 A0[4], A1[4];
    loadO(A0, w);
    if (w < 3) loadO(A1, w + 8);
    computeO(A0, w);
    if (w < 3) computeO(A1, w + 8);
}

// ---------------------------------------------------------------- launch
extern "C" void kernel_launch(void* const* d_in, const int* in_sizes, int n_in,
                              void* d_out, int out_size, void* d_ws, size_t ws_size,
                              hipStream_t stream) {
    const float* values = (const float*)d_in[0];
    const float* keys   = (const float*)d_in[1];
    const float* query  = (const float*)d_in[2];
    const float* Wv = (const float*)d_in[3];
    const float* bv = (const float*)d_in[4];
    const float* Wk = (const float*)d_in[5];
    const float* bk = (const float*)d_in[6];
    const float* Wq = (const float*)d_in[7];
    const float* bq = (const float*)d_in[8];
    const float* Wo = (const float*)d_in[9];
    const float* bo = (const float*)d_in[10];
    float* out = (float*)d_out;

    __bf16* qws = (__bf16*)d_ws;
    __bf16* kws = qws + QKV_ELEMS;
    __bf16* ows = kws + QKV_ELEMS;
    __bf16* wbf = ows + QKV_ELEMS;            // 4 x 16384 bf16, swizzled (+scaled Wq)
    __bf16* vt  = (__bf16*)d_out;             // V^T scratch in d_out, consumed by attn

    hipLaunchKernelGGL(wconv_kernel, dim3(256),  dim3(256), 0, stream, Wq, Wk, Wv, Wo, wbf);
    hipLaunchKernelGGL(qkv_kernel,   dim3(3 * BLKS_PER_IID), dim3(256), 0, stream,
                       query, keys, values, wbf, bq, bk, bv, qws, kws, vt);
    hipLaunchKernelGGL(attn_kernel,  dim3(2048), dim3(256), 0, stream, qws, kws, vt, ows);
    hipLaunchKernelGGL(oproj_kernel, dim3(512),  dim3(512), 0, stream, ows, wbf, bo, out);
}